// Round 1
// 5618.372 us; speedup vs baseline: 1.2372x; 1.2372x over previous
//
#include <hip/hip_runtime.h>
#include <math.h>

#define BSZ 512
#define NV 30
#define NT 24
#define SS 768                  // state row stride (x: 0..249, m: 250..749, pad: 750..767)
#define PL (80 * 24 * 512)      // packed ushorts per (layer, half): 80 nb-blocks x 24 kc x 512

typedef __attribute__((ext_vector_type(8))) short bf16x8;
typedef __attribute__((ext_vector_type(4))) float f32x4;

__device__ __forceinline__ unsigned short f2bf(float f) {
    unsigned u = __float_as_uint(f);
    u += 0x7fffu + ((u >> 16) & 1u);        // round-to-nearest-even
    return (unsigned short)(u >> 16);
}
__device__ __forceinline__ float bf2f(unsigned short h) {
    return __uint_as_float(((unsigned)h) << 16);
}
__device__ __forceinline__ f32x4 mm(bf16x8 a, bf16x8 b, f32x4 c) {
    return __builtin_amdgcn_mfma_f32_16x16x32_bf16(a, b, c, 0, 0, 0);
}
#define LD8(p) (*(const bf16x8*)(const void*)(p))

// ---------------- zero ----------------
__global__ void zero_kernel(float* p, int n) {
    int i = blockIdx.x * blockDim.x + threadIdx.x;
    int st = gridDim.x * blockDim.x;
    for (; i < n; i += st) p[i] = 0.f;
}

// ---------------- one-time weight pack: fp32 [750][N] -> hi/lo bf16 MFMA-B layout ----------------
// layout: Phi[((nb*24 + kc)*64 + lane)*8 + j] = bf16_hi(W[kc*32 + (lane>>4)*8 + j][nb*16 + (lane&15)])
// nb 0..31 = sw (N=500, pad to 512), 32..63 = mem, 64..79 = sv (N=250, pad to 256). k>=750 zero-padded.
__launch_bounds__(64)
__global__ void pack_weights(const float* __restrict__ Wsw, const float* __restrict__ Wmem,
                             const float* __restrict__ Wsv,
                             unsigned short* __restrict__ Phi, unsigned short* __restrict__ Plo)
{
    const int kc = blockIdx.x;   // 0..23
    const int nb = blockIdx.y;   // 0..79
    const int l  = threadIdx.x;  // 0..63
    const int g = l >> 4, c = l & 15;
    const float* W; int N, nbl;
    if (nb < 32)      { W = Wsw;  N = 500; nbl = nb; }
    else if (nb < 64) { W = Wmem; N = 500; nbl = nb - 32; }
    else              { W = Wsv;  N = 250; nbl = nb - 64; }
    const int n = nbl * 16 + c;
    unsigned short h8[8], l8[8];
    #pragma unroll
    for (int j = 0; j < 8; ++j) {
        const int k = kc * 32 + g * 8 + j;
        const float w = (k < 750 && n < N) ? W[(size_t)k * N + n] : 0.f;
        const unsigned short h = f2bf(w);
        h8[j] = h;
        l8[j] = f2bf(w - bf2f(h));
    }
    const size_t off = ((size_t)nb * 24 + kc) * 512 + (size_t)l * 8;
    #pragma unroll
    for (int j = 0; j < 8; ++j) { Phi[off + j] = h8[j]; Plo[off + j] = l8[j]; }
}

// ---------------- fused layer: bf16x2 MFMA GEMM + gate epilogue, 1 wave / block ----------------
// bid < 128: sw+mem tile (rows rt*32..+31, cols ct*64..+63 of both zsw and zmem) -> m update
// bid >= 128: sv tile (rows rt*32..+31, cols ct*64..+63 of zsv)                 -> x update
// bid = rt*8 + ct for sw/mem => bid%8 == ct: each XCD's L2 holds one 64-col weight panel.
__launch_bounds__(64)
__global__ void layer_fused(const float* __restrict__ Sf,
                            const unsigned short* __restrict__ Ahi,
                            const unsigned short* __restrict__ Alo,
                            float* __restrict__ So,
                            unsigned short* __restrict__ Ohi,
                            unsigned short* __restrict__ Olo,
                            const unsigned short* __restrict__ Phi,
                            const unsigned short* __restrict__ Plo,
                            const float* __restrict__ bsw, const float* __restrict__ bmem,
                            const float* __restrict__ bsv,
                            const float* __restrict__ W1sw, const float* __restrict__ W1mem,
                            const float* __restrict__ W1sv,
                            const int* __restrict__ letters, int t)
{
    const int l = threadIdx.x;
    const int g = l >> 4, c = l & 15;
    const int bid = blockIdx.x;
    const bool first = (letters != nullptr);

    if (bid < 128) {
        const int rt = bid >> 3, ct = bid & 7;
        const int m0 = rt * 32;
        f32x4 zsw[2][4], zmm[2][4];
        #pragma unroll
        for (int rb = 0; rb < 2; ++rb)
            #pragma unroll
            for (int cb = 0; cb < 4; ++cb) { zsw[rb][cb] = (f32x4)0.f; zmm[rb][cb] = (f32x4)0.f; }

        const size_t aoff = (size_t)(m0 + c) * SS + (size_t)g * 8;
        const unsigned short* pAh = Ahi + aoff;
        const unsigned short* pAl = Alo + aoff;
        const size_t bsw0 = ((size_t)(ct * 4) * 24) * 512 + (size_t)l * 8;
        const size_t bmm0 = ((size_t)(32 + ct * 4) * 24) * 512 + (size_t)l * 8;

        #pragma unroll 2
        for (int kc = 0; kc < 24; ++kc) {
            bf16x8 ah[2], al[2];
            #pragma unroll
            for (int rb = 0; rb < 2; ++rb) {
                ah[rb] = LD8(pAh + (size_t)rb * 16 * SS + kc * 32);
                al[rb] = LD8(pAl + (size_t)rb * 16 * SS + kc * 32);
            }
            #pragma unroll
            for (int cb = 0; cb < 4; ++cb) {
                const size_t osw = bsw0 + ((size_t)cb * 24 + kc) * 512;
                bf16x8 bh = LD8(Phi + osw);
                bf16x8 bl = LD8(Plo + osw);
                #pragma unroll
                for (int rb = 0; rb < 2; ++rb) {
                    zsw[rb][cb] = mm(ah[rb], bh, zsw[rb][cb]);
                    zsw[rb][cb] = mm(al[rb], bh, zsw[rb][cb]);
                    zsw[rb][cb] = mm(ah[rb], bl, zsw[rb][cb]);
                }
                const size_t omm = bmm0 + ((size_t)cb * 24 + kc) * 512;
                bh = LD8(Phi + omm);
                bl = LD8(Plo + omm);
                #pragma unroll
                for (int rb = 0; rb < 2; ++rb) {
                    zmm[rb][cb] = mm(ah[rb], bh, zmm[rb][cb]);
                    zmm[rb][cb] = mm(al[rb], bh, zmm[rb][cb]);
                    zmm[rb][cb] = mm(ah[rb], bl, zmm[rb][cb]);
                }
            }
        }

        // epilogue: D frag layout col = lane&15, row = (lane>>4)*4 + reg
        #pragma unroll
        for (int rb = 0; rb < 2; ++rb) {
            #pragma unroll
            for (int r = 0; r < 4; ++r) {
                const int row = m0 + rb * 16 + g * 4 + r;
                const int lt = first ? letters[row * NT + t] : 0;
                #pragma unroll
                for (int cb = 0; cb < 4; ++cb) {
                    const int col = ct * 64 + cb * 16 + c;
                    if (col < 500) {
                        float zs = zsw[rb][cb][r] + bsw[col];
                        float zm = zmm[rb][cb][r] + bmem[col];
                        if (first) {
                            zs += W1sw[(size_t)(750 + lt) * 500 + col];
                            zm += W1mem[(size_t)(750 + lt) * 500 + col];
                        }
                        const float s = 1.f / (1.f + expf(-zs));
                        const size_t o = (size_t)row * SS + 250 + col;
                        const float mo = Sf[o];
                        const float mn = mo * s + tanhf(zm) * (1.f - s);
                        So[o] = mn;
                        const unsigned short h = f2bf(mn);
                        Ohi[o] = h;
                        Olo[o] = f2bf(mn - bf2f(h));
                    }
                }
            }
        }
    } else {
        const int q = bid - 128;
        const int rt = q >> 2, ct = q & 3;
        const int m0 = rt * 32;
        f32x4 zsv[2][4];
        #pragma unroll
        for (int rb = 0; rb < 2; ++rb)
            #pragma unroll
            for (int cb = 0; cb < 4; ++cb) zsv[rb][cb] = (f32x4)0.f;

        const size_t aoff = (size_t)(m0 + c) * SS + (size_t)g * 8;
        const unsigned short* pAh = Ahi + aoff;
        const unsigned short* pAl = Alo + aoff;
        const size_t bsv0 = ((size_t)(64 + ct * 4) * 24) * 512 + (size_t)l * 8;

        #pragma unroll 2
        for (int kc = 0; kc < 24; ++kc) {
            bf16x8 ah[2], al[2];
            #pragma unroll
            for (int rb = 0; rb < 2; ++rb) {
                ah[rb] = LD8(pAh + (size_t)rb * 16 * SS + kc * 32);
                al[rb] = LD8(pAl + (size_t)rb * 16 * SS + kc * 32);
            }
            #pragma unroll
            for (int cb = 0; cb < 4; ++cb) {
                const size_t o = bsv0 + ((size_t)cb * 24 + kc) * 512;
                const bf16x8 bh = LD8(Phi + o);
                const bf16x8 bl = LD8(Plo + o);
                #pragma unroll
                for (int rb = 0; rb < 2; ++rb) {
                    zsv[rb][cb] = mm(ah[rb], bh, zsv[rb][cb]);
                    zsv[rb][cb] = mm(al[rb], bh, zsv[rb][cb]);
                    zsv[rb][cb] = mm(ah[rb], bl, zsv[rb][cb]);
                }
            }
        }

        #pragma unroll
        for (int rb = 0; rb < 2; ++rb) {
            #pragma unroll
            for (int r = 0; r < 4; ++r) {
                const int row = m0 + rb * 16 + g * 4 + r;
                const int lt = first ? letters[row * NT + t] : 0;
                #pragma unroll
                for (int cb = 0; cb < 4; ++cb) {
                    const int col = ct * 64 + cb * 16 + c;
                    if (col < 250) {
                        float z = zsv[rb][cb][r] + bsv[col];
                        if (first) z += W1sv[(size_t)(750 + lt) * 250 + col];
                        const float x = tanhf(z);
                        const size_t o = (size_t)row * SS + col;
                        So[o] = x;
                        const unsigned short h = f2bf(x);
                        Ohi[o] = h;
                        Olo[o] = f2bf(x - bf2f(h));
                    }
                }
            }
        }
    }
}

// ---------------- head GEMM: Y = tanh(X @ W + b) (fp32, unchanged) ----------------
__launch_bounds__(128)
__global__ void head_gemm(const float* __restrict__ X, int ldx, int K,
                          const float* __restrict__ W, const float* __restrict__ bias,
                          float* __restrict__ Y, int N)
{
    const int tid = threadIdx.x;
    const int m0 = blockIdx.y * 32;
    const int n0 = blockIdx.x * 64;

    __shared__ float As[2][32][36];
    __shared__ float Bs[2][32][68];

    const int tx = tid & 15, ty = tid >> 4;
    const int kl = tid & 31, rl = tid >> 5;
    const int cl = tid & 63, kg = tid >> 6;
    const bool cok = (n0 + cl) < N;

    float acc[4][4] = {{0.f}};
    float ar[8], br[16];

    {
        const float* a = X + (size_t)(m0 + rl) * ldx + kl;
        #pragma unroll
        for (int i = 0; i < 8; i++) ar[i] = a[(size_t)(4 * i) * ldx];
        #pragma unroll
        for (int i = 0; i < 16; i++)
            br[i] = cok ? W[(size_t)(kg + 2 * i) * N + n0 + cl] : 0.f;
        #pragma unroll
        for (int i = 0; i < 8; i++) As[0][kl][rl + 4 * i] = ar[i];
        #pragma unroll
        for (int i = 0; i < 16; i++) Bs[0][kg + 2 * i][cl] = br[i];
    }
    __syncthreads();

    int buf = 0;
    const int NK = (K + 31) / 32;
    #pragma unroll 1
    for (int kt = 0; kt < NK; kt++) {
        const bool more = (kt + 1 < NK);
        if (more) {
            const int k0 = (kt + 1) * 32;
            const bool ka = (k0 + kl) < K;
            const float* a = X + (size_t)(m0 + rl) * ldx + k0 + kl;
            #pragma unroll
            for (int i = 0; i < 8; i++) ar[i] = ka ? a[(size_t)(4 * i) * ldx] : 0.f;
            #pragma unroll
            for (int i = 0; i < 16; i++) {
                const int kk = k0 + kg + 2 * i;
                br[i] = (cok && kk < K) ? W[(size_t)kk * N + n0 + cl] : 0.f;
            }
        }
        #pragma unroll
        for (int kk = 0; kk < 32; kk++) {
            float4 av = *(const float4*)&As[buf][kk][ty * 4];
            float4 bv = *(const float4*)&Bs[buf][kk][tx * 4];
            const float aa[4] = {av.x, av.y, av.z, av.w};
            const float bb[4] = {bv.x, bv.y, bv.z, bv.w};
            #pragma unroll
            for (int i = 0; i < 4; i++)
                #pragma unroll
                for (int j = 0; j < 4; j++)
                    acc[i][j] = fmaf(aa[i], bb[j], acc[i][j]);
        }
        if (more) {
            #pragma unroll
            for (int i = 0; i < 8; i++) As[buf ^ 1][kl][rl + 4 * i] = ar[i];
            #pragma unroll
            for (int i = 0; i < 16; i++) Bs[buf ^ 1][kg + 2 * i][cl] = br[i];
            __syncthreads();
            buf ^= 1;
        }
    }

    #pragma unroll
    for (int i = 0; i < 4; i++) {
        const int b = m0 + ty * 4 + i;
        #pragma unroll
        for (int j = 0; j < 4; j++) {
            const int n = n0 + tx * 4 + j;
            if (n < N) Y[(size_t)b * N + n] = tanhf(acc[i][j] + bias[n]);
        }
    }
}

// ---------------- final: logits (K=100, N=30) + softmax ----------------
__global__ void head_final(const float* __restrict__ Y4, const float* __restrict__ W,
                           const float* __restrict__ bias, float* __restrict__ out)
{
    const int row = blockIdx.x;
    __shared__ float y[100];
    __shared__ float z[NV];
    for (int k = threadIdx.x; k < 100; k += 64) y[k] = Y4[row * 100 + k];
    __syncthreads();
    const int n = threadIdx.x;
    if (n < NV) {
        float acc = bias[n];
        for (int k = 0; k < 100; k++) acc = fmaf(y[k], W[k * NV + n], acc);
        z[n] = acc;
    }
    __syncthreads();
    if (n < NV) {
        float mx = -1e30f;
        for (int i = 0; i < NV; i++) mx = fmaxf(mx, z[i]);
        float sum = 0.f;
        for (int i = 0; i < NV; i++) sum += expf(z[i] - mx);
        out[row * NV + n] = expf(z[n] - mx) / sum;
    }
}

extern "C" void kernel_launch(void* const* d_in, const int* in_sizes, int n_in,
                              void* d_out, int out_size, void* d_ws, size_t ws_size,
                              hipStream_t stream)
{
    const int*   letters = (const int*)  d_in[0];
    const float* w1_sv   = (const float*)d_in[1];
    const float* b1_sv   = (const float*)d_in[2];
    const float* w1_mem  = (const float*)d_in[3];
    const float* b1_mem  = (const float*)d_in[4];
    const float* w1_sw   = (const float*)d_in[5];
    const float* b1_sw   = (const float*)d_in[6];
    const float* w_sv    = (const float*)d_in[7];
    const float* b_sv    = (const float*)d_in[8];
    const float* w_mem   = (const float*)d_in[9];
    const float* b_mem   = (const float*)d_in[10];
    const float* w_sw    = (const float*)d_in[11];
    const float* b_sw    = (const float*)d_in[12];
    const float* wp1 = (const float*)d_in[13]; const float* bp1 = (const float*)d_in[14];
    const float* wp2 = (const float*)d_in[15]; const float* bp2 = (const float*)d_in[16];
    const float* wp3 = (const float*)d_in[17]; const float* bp3 = (const float*)d_in[18];
    const float* wp4 = (const float*)d_in[19]; const float* bp4 = (const float*)d_in[20];
    const float* wp5 = (const float*)d_in[21]; const float* bp5 = (const float*)d_in[22];

    // workspace layout
    float* S0f = (float*)d_ws;
    float* S1f = S0f + (size_t)BSZ * SS;
    unsigned short* A0hi = (unsigned short*)(S1f + (size_t)BSZ * SS);
    unsigned short* A0lo = A0hi + (size_t)BSZ * SS;
    unsigned short* A1hi = A0lo + (size_t)BSZ * SS;
    unsigned short* A1lo = A1hi + (size_t)BSZ * SS;
    unsigned short* Pw   = A1lo + (size_t)BSZ * SS;   // 12 * PL ushorts
    float* Y1 = (float*)(Pw + (size_t)12 * PL);
    float* Y2 = Y1 + (size_t)BSZ * 450;
    float* Y3 = Y2 + (size_t)BSZ * 300;
    float* Y4 = Y3 + (size_t)BSZ * 200;

    // zero fp32 states + all hi/lo state buffers (incl. K-pad cols 750..767, which stay 0 forever)
    zero_kernel<<<512, 256, 0, stream>>>(S0f, 4 * BSZ * SS);

    // one-time weight packing (6 launches)
    pack_weights<<<dim3(24, 80), 64, 0, stream>>>(w1_sw, w1_mem, w1_sv, Pw, Pw + PL);
    for (int l = 1; l < 6; ++l)
        pack_weights<<<dim3(24, 80), 64, 0, stream>>>(
            w_sw  + (size_t)(l - 1) * 750 * 500,
            w_mem + (size_t)(l - 1) * 750 * 500,
            w_sv  + (size_t)(l - 1) * 750 * 250,
            Pw + (size_t)l * 2 * PL, Pw + (size_t)l * 2 * PL + PL);

    float* curF = S0f;  float* nxtF = S1f;
    unsigned short* curHi = A0hi; unsigned short* curLo = A0lo;
    unsigned short* nxtHi = A1hi; unsigned short* nxtLo = A1lo;

    for (int t = 0; t < NT; t++) {
        for (int l = 0; l < 6; l++) {
            const unsigned short* Phi = Pw + (size_t)l * 2 * PL;
            const unsigned short* Plo = Phi + PL;
            const float* bsw  = l ? b_sw  + (size_t)(l - 1) * 500 : b1_sw;
            const float* bmem = l ? b_mem + (size_t)(l - 1) * 500 : b1_mem;
            const float* bsv  = l ? b_sv  + (size_t)(l - 1) * 250 : b1_sv;
            layer_fused<<<192, 64, 0, stream>>>(curF, curHi, curLo, nxtF, nxtHi, nxtLo,
                Phi, Plo, bsw, bmem, bsv,
                l ? nullptr : w1_sw, l ? nullptr : w1_mem, l ? nullptr : w1_sv,
                l ? nullptr : letters, t);
            { float* tf = curF; curF = nxtF; nxtF = tf; }
            { unsigned short* th = curHi; curHi = nxtHi; nxtHi = th; }
            { unsigned short* tl = curLo; curLo = nxtLo; nxtLo = tl; }
        }
    }

    head_gemm<<<dim3(8, 16), 128, 0, stream>>>(curF, SS, 750, wp1, bp1, Y1, 450);
    head_gemm<<<dim3(5, 16), 128, 0, stream>>>(Y1, 450, 450, wp2, bp2, Y2, 300);
    head_gemm<<<dim3(4, 16), 128, 0, stream>>>(Y2, 300, 300, wp3, bp3, Y3, 200);
    head_gemm<<<dim3(2, 16), 128, 0, stream>>>(Y3, 200, 200, wp4, bp4, Y4, 100);
    head_final<<<BSZ, 64, 0, stream>>>(Y4, wp5, bp5, (float*)d_out);
}

// Round 2
// 3536.526 us; speedup vs baseline: 1.9655x; 1.5887x over previous
//
#include <hip/hip_runtime.h>
#include <math.h>

#define BSZ 512
#define NV 30
#define NT 24
#define SS 768                  // state row stride (x: 0..249, m: 250..749, pad: 750..767)
#define PL (80 * 24 * 512)      // packed ushorts per (layer, half): 80 nb-blocks x 24 kc x 512

typedef __attribute__((ext_vector_type(8))) short bf16x8;
typedef __attribute__((ext_vector_type(4))) float f32x4;

__device__ __forceinline__ unsigned short f2bf(float f) {
    unsigned u = __float_as_uint(f);
    u += 0x7fffu + ((u >> 16) & 1u);        // round-to-nearest-even
    return (unsigned short)(u >> 16);
}
__device__ __forceinline__ float bf2f(unsigned short h) {
    return __uint_as_float(((unsigned)h) << 16);
}
__device__ __forceinline__ f32x4 mm(bf16x8 a, bf16x8 b, f32x4 c) {
    return __builtin_amdgcn_mfma_f32_16x16x32_bf16(a, b, c, 0, 0, 0);
}
#define LD8(p) (*(const bf16x8*)(const void*)(p))

// ---------------- zero ----------------
__global__ void zero_kernel(float* p, int n) {
    int i = blockIdx.x * blockDim.x + threadIdx.x;
    int st = gridDim.x * blockDim.x;
    for (; i < n; i += st) p[i] = 0.f;
}

// ---------------- one-time weight pack: fp32 [750][N] -> hi/lo bf16 MFMA-B layout ----------------
// layout: Phi[((nb*24 + kc)*64 + lane)*8 + j] = bf16_hi(W[kc*32 + (lane>>4)*8 + j][nb*16 + (lane&15)])
// nb 0..31 = sw (N=500, pad to 512), 32..63 = mem, 64..79 = sv (N=250, pad to 256). k>=750 zero-padded.
__launch_bounds__(64)
__global__ void pack_weights(const float* __restrict__ Wsw, const float* __restrict__ Wmem,
                             const float* __restrict__ Wsv,
                             unsigned short* __restrict__ Phi, unsigned short* __restrict__ Plo)
{
    const int kc = blockIdx.x;   // 0..23
    const int nb = blockIdx.y;   // 0..79
    const int l  = threadIdx.x;  // 0..63
    const int g = l >> 4, c = l & 15;
    const float* W; int N, nbl;
    if (nb < 32)      { W = Wsw;  N = 500; nbl = nb; }
    else if (nb < 64) { W = Wmem; N = 500; nbl = nb - 32; }
    else              { W = Wsv;  N = 250; nbl = nb - 64; }
    const int n = nbl * 16 + c;
    unsigned short h8[8], l8[8];
    #pragma unroll
    for (int j = 0; j < 8; ++j) {
        const int k = kc * 32 + g * 8 + j;
        const float w = (k < 750 && n < N) ? W[(size_t)k * N + n] : 0.f;
        const unsigned short h = f2bf(w);
        h8[j] = h;
        l8[j] = f2bf(w - bf2f(h));
    }
    const size_t off = ((size_t)nb * 24 + kc) * 512 + (size_t)l * 8;
    #pragma unroll
    for (int j = 0; j < 8; ++j) { Phi[off + j] = h8[j]; Plo[off + j] = l8[j]; }
}

// ---------------- fused layer: bf16x2 MFMA GEMM + gate epilogue ----------------
// 256 threads = 4 waves. Wave w owns column-fragment cb = w (16 cols).
// bid < 128: sw+mem tile (rows rt*32..+31, cols ct*64..+63) -> m update; bid%8 == ct (XCD L2 affinity)
// bid >= 128: sv tile -> x update.
// No LDS, no barriers: each wave's epilogue only needs its own accumulators.
__launch_bounds__(256)
__global__ void layer_fused(const float* __restrict__ Sf,
                            const unsigned short* __restrict__ Ahi,
                            const unsigned short* __restrict__ Alo,
                            float* __restrict__ So,
                            unsigned short* __restrict__ Ohi,
                            unsigned short* __restrict__ Olo,
                            const unsigned short* __restrict__ Phi,
                            const unsigned short* __restrict__ Plo,
                            const float* __restrict__ bsw, const float* __restrict__ bmem,
                            const float* __restrict__ bsv,
                            const float* __restrict__ W1sw, const float* __restrict__ W1mem,
                            const float* __restrict__ W1sv,
                            const int* __restrict__ letters, int t)
{
    const int tid = threadIdx.x;
    const int wv = tid >> 6;         // 0..3 = this wave's cb
    const int l  = tid & 63;
    const int g = l >> 4, c = l & 15;
    const int bid = blockIdx.x;
    const bool first = (letters != nullptr);

    if (bid < 128) {
        const int rt = bid >> 3, ct = bid & 7;
        const int m0 = rt * 32;
        f32x4 zsw[2], zmm[2];
        zsw[0] = (f32x4)0.f; zsw[1] = (f32x4)0.f;
        zmm[0] = (f32x4)0.f; zmm[1] = (f32x4)0.f;

        const size_t aoff = (size_t)(m0 + c) * SS + (size_t)g * 8;
        const unsigned short* pAh = Ahi + aoff;
        const unsigned short* pAl = Alo + aoff;
        const size_t bsw0 = ((size_t)(ct * 4 + wv) * 24) * 512 + (size_t)l * 8;
        const size_t bmm0 = ((size_t)(32 + ct * 4 + wv) * 24) * 512 + (size_t)l * 8;

        #pragma unroll 4
        for (int kc = 0; kc < 24; ++kc) {
            const bf16x8 ah0 = LD8(pAh + kc * 32);
            const bf16x8 ah1 = LD8(pAh + (size_t)16 * SS + kc * 32);
            const bf16x8 al0 = LD8(pAl + kc * 32);
            const bf16x8 al1 = LD8(pAl + (size_t)16 * SS + kc * 32);
            bf16x8 bh = LD8(Phi + bsw0 + (size_t)kc * 512);
            bf16x8 bl = LD8(Plo + bsw0 + (size_t)kc * 512);
            zsw[0] = mm(ah0, bh, zsw[0]); zsw[0] = mm(al0, bh, zsw[0]); zsw[0] = mm(ah0, bl, zsw[0]);
            zsw[1] = mm(ah1, bh, zsw[1]); zsw[1] = mm(al1, bh, zsw[1]); zsw[1] = mm(ah1, bl, zsw[1]);
            bh = LD8(Phi + bmm0 + (size_t)kc * 512);
            bl = LD8(Plo + bmm0 + (size_t)kc * 512);
            zmm[0] = mm(ah0, bh, zmm[0]); zmm[0] = mm(al0, bh, zmm[0]); zmm[0] = mm(ah0, bl, zmm[0]);
            zmm[1] = mm(ah1, bh, zmm[1]); zmm[1] = mm(al1, bh, zmm[1]); zmm[1] = mm(ah1, bl, zmm[1]);
        }

        // epilogue: D frag layout col = lane&15, row = (lane>>4)*4 + reg
        const int col = ct * 64 + wv * 16 + c;
        #pragma unroll
        for (int rb = 0; rb < 2; ++rb) {
            #pragma unroll
            for (int r = 0; r < 4; ++r) {
                const int row = m0 + rb * 16 + g * 4 + r;
                if (col < 500) {
                    float zs = zsw[rb][r] + bsw[col];
                    float zm = zmm[rb][r] + bmem[col];
                    if (first) {
                        const int lt = letters[row * NT + t];
                        zs += W1sw[(size_t)(750 + lt) * 500 + col];
                        zm += W1mem[(size_t)(750 + lt) * 500 + col];
                    }
                    const float s = 1.f / (1.f + expf(-zs));
                    const size_t o = (size_t)row * SS + 250 + col;
                    const float mo = Sf[o];
                    const float mn = mo * s + tanhf(zm) * (1.f - s);
                    So[o] = mn;
                    const unsigned short h = f2bf(mn);
                    Ohi[o] = h;
                    Olo[o] = f2bf(mn - bf2f(h));
                }
            }
        }
    } else {
        const int q = bid - 128;
        const int rt = q >> 2, ct = q & 3;
        const int m0 = rt * 32;
        f32x4 zsv[2];
        zsv[0] = (f32x4)0.f; zsv[1] = (f32x4)0.f;

        const size_t aoff = (size_t)(m0 + c) * SS + (size_t)g * 8;
        const unsigned short* pAh = Ahi + aoff;
        const unsigned short* pAl = Alo + aoff;
        const size_t bsv0 = ((size_t)(64 + ct * 4 + wv) * 24) * 512 + (size_t)l * 8;

        #pragma unroll 4
        for (int kc = 0; kc < 24; ++kc) {
            const bf16x8 ah0 = LD8(pAh + kc * 32);
            const bf16x8 ah1 = LD8(pAh + (size_t)16 * SS + kc * 32);
            const bf16x8 al0 = LD8(pAl + kc * 32);
            const bf16x8 al1 = LD8(pAl + (size_t)16 * SS + kc * 32);
            const bf16x8 bh = LD8(Phi + bsv0 + (size_t)kc * 512);
            const bf16x8 bl = LD8(Plo + bsv0 + (size_t)kc * 512);
            zsv[0] = mm(ah0, bh, zsv[0]); zsv[0] = mm(al0, bh, zsv[0]); zsv[0] = mm(ah0, bl, zsv[0]);
            zsv[1] = mm(ah1, bh, zsv[1]); zsv[1] = mm(al1, bh, zsv[1]); zsv[1] = mm(ah1, bl, zsv[1]);
        }

        const int col = ct * 64 + wv * 16 + c;
        #pragma unroll
        for (int rb = 0; rb < 2; ++rb) {
            #pragma unroll
            for (int r = 0; r < 4; ++r) {
                const int row = m0 + rb * 16 + g * 4 + r;
                if (col < 250) {
                    float z = zsv[rb][r] + bsv[col];
                    if (first) {
                        const int lt = letters[row * NT + t];
                        z += W1sv[(size_t)(750 + lt) * 250 + col];
                    }
                    const float x = tanhf(z);
                    const size_t o = (size_t)row * SS + col;
                    So[o] = x;
                    const unsigned short h = f2bf(x);
                    Ohi[o] = h;
                    Olo[o] = f2bf(x - bf2f(h));
                }
            }
        }
    }
}

// ---------------- head GEMM: Y = tanh(X @ W + b) (fp32, unchanged) ----------------
__launch_bounds__(128)
__global__ void head_gemm(const float* __restrict__ X, int ldx, int K,
                          const float* __restrict__ W, const float* __restrict__ bias,
                          float* __restrict__ Y, int N)
{
    const int tid = threadIdx.x;
    const int m0 = blockIdx.y * 32;
    const int n0 = blockIdx.x * 64;

    __shared__ float As[2][32][36];
    __shared__ float Bs[2][32][68];

    const int tx = tid & 15, ty = tid >> 4;
    const int kl = tid & 31, rl = tid >> 5;
    const int cl = tid & 63, kg = tid >> 6;
    const bool cok = (n0 + cl) < N;

    float acc[4][4] = {{0.f}};
    float ar[8], br[16];

    {
        const float* a = X + (size_t)(m0 + rl) * ldx + kl;
        #pragma unroll
        for (int i = 0; i < 8; i++) ar[i] = a[(size_t)(4 * i) * ldx];
        #pragma unroll
        for (int i = 0; i < 16; i++)
            br[i] = cok ? W[(size_t)(kg + 2 * i) * N + n0 + cl] : 0.f;
        #pragma unroll
        for (int i = 0; i < 8; i++) As[0][kl][rl + 4 * i] = ar[i];
        #pragma unroll
        for (int i = 0; i < 16; i++) Bs[0][kg + 2 * i][cl] = br[i];
    }
    __syncthreads();

    int buf = 0;
    const int NK = (K + 31) / 32;
    #pragma unroll 1
    for (int kt = 0; kt < NK; kt++) {
        const bool more = (kt + 1 < NK);
        if (more) {
            const int k0 = (kt + 1) * 32;
            const bool ka = (k0 + kl) < K;
            const float* a = X + (size_t)(m0 + rl) * ldx + k0 + kl;
            #pragma unroll
            for (int i = 0; i < 8; i++) ar[i] = ka ? a[(size_t)(4 * i) * ldx] : 0.f;
            #pragma unroll
            for (int i = 0; i < 16; i++) {
                const int kk = k0 + kg + 2 * i;
                br[i] = (cok && kk < K) ? W[(size_t)kk * N + n0 + cl] : 0.f;
            }
        }
        #pragma unroll
        for (int kk = 0; kk < 32; kk++) {
            float4 av = *(const float4*)&As[buf][kk][ty * 4];
            float4 bv = *(const float4*)&Bs[buf][kk][tx * 4];
            const float aa[4] = {av.x, av.y, av.z, av.w};
            const float bb[4] = {bv.x, bv.y, bv.z, bv.w};
            #pragma unroll
            for (int i = 0; i < 4; i++)
                #pragma unroll
                for (int j = 0; j < 4; j++)
                    acc[i][j] = fmaf(aa[i], bb[j], acc[i][j]);
        }
        if (more) {
            #pragma unroll
            for (int i = 0; i < 8; i++) As[buf ^ 1][kl][rl + 4 * i] = ar[i];
            #pragma unroll
            for (int i = 0; i < 16; i++) Bs[buf ^ 1][kg + 2 * i][cl] = br[i];
            __syncthreads();
            buf ^= 1;
        }
    }

    #pragma unroll
    for (int i = 0; i < 4; i++) {
        const int b = m0 + ty * 4 + i;
        #pragma unroll
        for (int j = 0; j < 4; j++) {
            const int n = n0 + tx * 4 + j;
            if (n < N) Y[(size_t)b * N + n] = tanhf(acc[i][j] + bias[n]);
        }
    }
}

// ---------------- final: logits (K=100, N=30) + softmax ----------------
__global__ void head_final(const float* __restrict__ Y4, const float* __restrict__ W,
                           const float* __restrict__ bias, float* __restrict__ out)
{
    const int row = blockIdx.x;
    __shared__ float y[100];
    __shared__ float z[NV];
    for (int k = threadIdx.x; k < 100; k += 64) y[k] = Y4[row * 100 + k];
    __syncthreads();
    const int n = threadIdx.x;
    if (n < NV) {
        float acc = bias[n];
        for (int k = 0; k < 100; k++) acc = fmaf(y[k], W[k * NV + n], acc);
        z[n] = acc;
    }
    __syncthreads();
    if (n < NV) {
        float mx = -1e30f;
        for (int i = 0; i < NV; i++) mx = fmaxf(mx, z[i]);
        float sum = 0.f;
        for (int i = 0; i < NV; i++) sum += expf(z[i] - mx);
        out[row * NV + n] = expf(z[n] - mx) / sum;
    }
}

extern "C" void kernel_launch(void* const* d_in, const int* in_sizes, int n_in,
                              void* d_out, int out_size, void* d_ws, size_t ws_size,
                              hipStream_t stream)
{
    const int*   letters = (const int*)  d_in[0];
    const float* w1_sv   = (const float*)d_in[1];
    const float* b1_sv   = (const float*)d_in[2];
    const float* w1_mem  = (const float*)d_in[3];
    const float* b1_mem  = (const float*)d_in[4];
    const float* w1_sw   = (const float*)d_in[5];
    const float* b1_sw   = (const float*)d_in[6];
    const float* w_sv    = (const float*)d_in[7];
    const float* b_sv    = (const float*)d_in[8];
    const float* w_mem   = (const float*)d_in[9];
    const float* b_mem   = (const float*)d_in[10];
    const float* w_sw    = (const float*)d_in[11];
    const float* b_sw    = (const float*)d_in[12];
    const float* wp1 = (const float*)d_in[13]; const float* bp1 = (const float*)d_in[14];
    const float* wp2 = (const float*)d_in[15]; const float* bp2 = (const float*)d_in[16];
    const float* wp3 = (const float*)d_in[17]; const float* bp3 = (const float*)d_in[18];
    const float* wp4 = (const float*)d_in[19]; const float* bp4 = (const float*)d_in[20];
    const float* wp5 = (const float*)d_in[21]; const float* bp5 = (const float*)d_in[22];

    // workspace layout
    float* S0f = (float*)d_ws;
    float* S1f = S0f + (size_t)BSZ * SS;
    unsigned short* A0hi = (unsigned short*)(S1f + (size_t)BSZ * SS);
    unsigned short* A0lo = A0hi + (size_t)BSZ * SS;
    unsigned short* A1hi = A0lo + (size_t)BSZ * SS;
    unsigned short* A1lo = A1hi + (size_t)BSZ * SS;
    unsigned short* Pw   = A1lo + (size_t)BSZ * SS;   // 12 * PL ushorts
    float* Y1 = (float*)(Pw + (size_t)12 * PL);
    float* Y2 = Y1 + (size_t)BSZ * 450;
    float* Y3 = Y2 + (size_t)BSZ * 300;
    float* Y4 = Y3 + (size_t)BSZ * 200;

    // zero fp32 states + all hi/lo state buffers (incl. K-pad cols 750..767, which stay 0 forever)
    zero_kernel<<<512, 256, 0, stream>>>(S0f, 4 * BSZ * SS);

    // one-time weight packing (6 launches)
    pack_weights<<<dim3(24, 80), 64, 0, stream>>>(w1_sw, w1_mem, w1_sv, Pw, Pw + PL);
    for (int l = 1; l < 6; ++l)
        pack_weights<<<dim3(24, 80), 64, 0, stream>>>(
            w_sw  + (size_t)(l - 1) * 750 * 500,
            w_mem + (size_t)(l - 1) * 750 * 500,
            w_sv  + (size_t)(l - 1) * 750 * 250,
            Pw + (size_t)l * 2 * PL, Pw + (size_t)l * 2 * PL + PL);

    float* curF = S0f;  float* nxtF = S1f;
    unsigned short* curHi = A0hi; unsigned short* curLo = A0lo;
    unsigned short* nxtHi = A1hi; unsigned short* nxtLo = A1lo;

    for (int t = 0; t < NT; t++) {
        for (int l = 0; l < 6; l++) {
            const unsigned short* Phi = Pw + (size_t)l * 2 * PL;
            const unsigned short* Plo = Phi + PL;
            const float* bsw  = l ? b_sw  + (size_t)(l - 1) * 500 : b1_sw;
            const float* bmem = l ? b_mem + (size_t)(l - 1) * 500 : b1_mem;
            const float* bsv  = l ? b_sv  + (size_t)(l - 1) * 250 : b1_sv;
            layer_fused<<<192, 256, 0, stream>>>(curF, curHi, curLo, nxtF, nxtHi, nxtLo,
                Phi, Plo, bsw, bmem, bsv,
                l ? nullptr : w1_sw, l ? nullptr : w1_mem, l ? nullptr : w1_sv,
                l ? nullptr : letters, t);
            { float* tf = curF; curF = nxtF; nxtF = tf; }
            { unsigned short* th = curHi; curHi = nxtHi; nxtHi = th; }
            { unsigned short* tl = curLo; curLo = nxtLo; nxtLo = tl; }
        }
    }

    head_gemm<<<dim3(8, 16), 128, 0, stream>>>(curF, SS, 750, wp1, bp1, Y1, 450);
    head_gemm<<<dim3(5, 16), 128, 0, stream>>>(Y1, 450, 450, wp2, bp2, Y2, 300);
    head_gemm<<<dim3(4, 16), 128, 0, stream>>>(Y2, 300, 300, wp3, bp3, Y3, 200);
    head_gemm<<<dim3(2, 16), 128, 0, stream>>>(Y3, 200, 200, wp4, bp4, Y4, 100);
    head_final<<<BSZ, 64, 0, stream>>>(Y4, wp5, bp5, (float*)d_out);
}